// Round 5
// baseline (333.388 us; speedup 1.0000x reference)
//
#include <hip/hip_runtime.h>
#include <hip/hip_bf16.h>
#include <stdint.h>

#define NN 32768
#define HH 256

typedef short bf16x8 __attribute__((ext_vector_type(8)));
typedef float f32x4 __attribute__((ext_vector_type(4)));
typedef unsigned short ushort_t;
typedef unsigned short ushort8_t __attribute__((ext_vector_type(8)));
typedef unsigned short ushort4_t __attribute__((ext_vector_type(4)));

__device__ __forceinline__ ushort_t f2bf(float f) {
  union { float f; unsigned u; } v; v.f = f;
  unsigned u = v.u;
  unsigned r = (u + 0x7FFFu + ((u >> 16) & 1u)) >> 16;  // RNE (cold paths)
  return (ushort_t)r;
}
__device__ __forceinline__ float bf2f(ushort_t h) {
  union { unsigned u; float f; } v; v.u = ((unsigned)h) << 16;
  return v.f;
}
__device__ __forceinline__ float asf(unsigned u) {
  union { unsigned u; float f; } v; v.u = u; return v.f;
}
// HW packed f32->bf16 (RNE), 1 instr per 2 elems
__device__ __forceinline__ unsigned cvt_pk(float lo, float hi) {
  unsigned r;
  asm("v_cvt_pk_bf16_f32 %0, %1, %2" : "=v"(r) : "v"(lo), "v"(hi));
  return r;
}
__device__ __forceinline__ float sigmoidf_(float x) {
  float e = __builtin_amdgcn_exp2f(-1.4426950408889634f * x);
  return __builtin_amdgcn_rcpf(1.f + e);
}
__device__ __forceinline__ float tanhf_(float x) {
  float ax = fminf(fabsf(x), 15.f);
  float e = __builtin_amdgcn_exp2f(2.8853900817779268f * ax);  // exp(2ax)
  float t = (e - 1.f) * __builtin_amdgcn_rcpf(e + 1.f);
  return copysignf(t, x);
}
// XOR swizzle: 16B chunks within a 256-elem (512B) row, spread across rows&7
__device__ __forceinline__ int swz(int row, int col) {
  return row * 256 + ((((col >> 3) ^ (row & 7)) << 3) | (col & 7));
}

// ---------------- prep: weights -> bf16, transposed to [N][K] ----------------
__global__ void k_prep(const float* __restrict__ W_iou, const float* __restrict__ W_fin,
                       const float* __restrict__ W_f, const float* __restrict__ W_aggr,
                       ushort_t* __restrict__ WcatT, ushort_t* __restrict__ WfT,
                       ushort_t* __restrict__ WaggrT) {
  int tid = blockIdx.x * 256 + threadIdx.x;
  if (tid < 262144) {                       // WcatT [1024][256]
    int n = tid >> 8, k = tid & 255;
    float v = (n < 768) ? W_iou[k * 768 + n] : W_fin[k * 256 + (n - 768)];
    WcatT[tid] = f2bf(v);
  } else if (tid < 327680) {                // WfT [256][256]
    int t2 = tid - 262144; int n = t2 >> 8, k = t2 & 255;
    WfT[t2] = f2bf(W_f[k * 256 + n]);
  } else if (tid < 524288) {                // WaggrT [768][256]
    int t3 = tid - 327680; int n = t3 >> 8, k = t3 & 255;
    WaggrT[t3] = f2bf(W_aggr[k * 768 + n]);
  }
}

// ---------------- k1: iouf = x @ [W_iou | W_fin] + bias ---------------------- 
__global__ __launch_bounds__(256) void k_iou(
    const float* __restrict__ x, const ushort_t* __restrict__ WcatT,
    const float* __restrict__ b_iou, const float* __restrict__ b_fin,
    ushort_t* __restrict__ io_out, ushort_t* __restrict__ cau_out,
    ushort_t* __restrict__ f_out) {
  __shared__ __align__(16) ushort_t As[64 * 256];
  __shared__ __align__(16) ushort_t Bs[64 * 256];
  __shared__ float bias_s[64];
  const int tid = threadIdx.x;
  const int mt = blockIdx.x >> 2;
  const int nt = blockIdx.x & 3;

  const float4* Ag = (const float4*)(x + (size_t)mt * 64 * 256);
#pragma unroll
  for (int it = 0; it < 16; ++it) {
    int idx4 = tid + it * 256;
    float4 v = Ag[idx4];
    int row = idx4 >> 6, col = (idx4 & 63) << 2;
    uint2 b = { cvt_pk(v.x, v.y), cvt_pk(v.z, v.w) };
    *(uint2*)&As[swz(row, col)] = b;
  }

  const int lane = tid & 63, wv = tid >> 6;
  const int g = lane >> 4, r = lane & 15;
  const int wm = wv >> 1, wn = wv & 1;

  for (int s = 0; s < 4; ++s) {
    __syncthreads();
    const int ct = nt * 4 + s;  // 64-col tile index in [0,16)
    const ushort8_t* Bg = (const ushort8_t*)(WcatT + (size_t)ct * 64 * 256);
#pragma unroll
    for (int it = 0; it < 8; ++it) {
      int idx8 = tid + it * 256;
      int row = idx8 >> 5, col = (idx8 & 31) << 3;
      *(ushort8_t*)&Bs[swz(row, col)] = Bg[idx8];
    }
    if (tid < 64) {
      int c = ct * 64 + tid;
      bias_s[tid] = (c < 768) ? b_iou[c] : b_fin[c - 768];
    }
    __syncthreads();

    f32x4 acc[2][2] = {};
#pragma unroll
    for (int kb = 0; kb < 8; ++kb) {
      int kc = kb * 32 + g * 8;
      bf16x8 a0 = *(const bf16x8*)&As[swz(wm * 32 + r, kc)];
      bf16x8 a1 = *(const bf16x8*)&As[swz(wm * 32 + 16 + r, kc)];
      bf16x8 b0 = *(const bf16x8*)&Bs[swz(wn * 32 + r, kc)];
      bf16x8 b1 = *(const bf16x8*)&Bs[swz(wn * 32 + 16 + r, kc)];
      acc[0][0] = __builtin_amdgcn_mfma_f32_16x16x32_bf16(a0, b0, acc[0][0], 0, 0, 0);
      acc[0][1] = __builtin_amdgcn_mfma_f32_16x16x32_bf16(a0, b1, acc[0][1], 0, 0, 0);
      acc[1][0] = __builtin_amdgcn_mfma_f32_16x16x32_bf16(a1, b0, acc[1][0], 0, 0, 0);
      acc[1][1] = __builtin_amdgcn_mfma_f32_16x16x32_bf16(a1, b1, acc[1][1], 0, 0, 0);
    }
#pragma unroll
    for (int mi = 0; mi < 2; ++mi)
#pragma unroll
      for (int ni = 0; ni < 2; ++ni)
#pragma unroll
        for (int i = 0; i < 4; ++i) {
          int node = mt * 64 + wm * 32 + mi * 16 + g * 4 + i;
          int colL = wn * 32 + ni * 16 + r;
          int col = ct * 64 + colL;
          ushort_t hv = f2bf(acc[mi][ni][i] + bias_s[colL]);
          if (col < 512)      io_out[node * 512 + col] = hv;
          else if (col < 768) cau_out[node * 512 + (col - 256)] = hv;
          else                f_out[node * 256 + (col - 768)] = hv;
        }
  }
}

// ---------------- k2: f-path v4 — single tile, single barrier ----------------
// Block = 64 nh rows (8 nodes) x all 256 cols, 8 waves. Wave w owns 32 cols,
// W_f^T register-resident. hsum fused into staging with zero shfl (lane loads
// all 8 children of its 4-col chunk). 4096 blocks -> inter-block overlap.
__global__ __launch_bounds__(512, 4) void k_fgate(
    const float* __restrict__ nh, const float* __restrict__ nc,
    const ushort_t* __restrict__ WfT, const float* __restrict__ b_f,
    const ushort_t* __restrict__ f_in,
    ushort_t* __restrict__ cau_out, ushort_t* __restrict__ hsum_out) {
  __shared__ __align__(16) ushort_t As[64 * 256];   // 32 KB
  const int tid = threadIdx.x;
  const size_t blk = blockIdx.x;                    // 64 rows per block
  const int lane = tid & 63, wv = tid >> 6;
  const int g = lane >> 4, r = lane & 15;
  const int mb = wv * 32;                           // wave's W-col base

  // W_f^T fragments (B-operand), register-resident; issue early
  bf16x8 wfrag[2][8];
#pragma unroll
  for (int ct = 0; ct < 2; ++ct)
#pragma unroll
    for (int kb = 0; kb < 8; ++kb)
      wfrag[ct][kb] = *(const bf16x8*)&WfT[(mb + ct * 16 + r) * 256 + kb * 32 + g * 8];
  float bias[2] = { b_f[mb + r], b_f[mb + 16 + r] };

  // stage 64 rows f32->bf16 + fused hsum (wave wv == node wv, lane == col-quad)
  {
    const float* src = nh + (blk * 64 + wv * 8) * 256 + lane * 4;
    float4 v[8];
#pragma unroll
    for (int c = 0; c < 8; ++c) v[c] = *(const float4*)(src + c * 256);
#pragma unroll
    for (int c = 0; c < 8; ++c) {
      uint2 p = { cvt_pk(v[c].x, v[c].y), cvt_pk(v[c].z, v[c].w) };
      *(uint2*)&As[swz(wv * 8 + c, lane * 4)] = p;
    }
    float s0 = 0.f, s1 = 0.f, s2 = 0.f, s3 = 0.f;
#pragma unroll
    for (int c = 0; c < 8; ++c) { s0 += v[c].x; s1 += v[c].y; s2 += v[c].z; s3 += v[c].w; }
    uint2 o = { cvt_pk(s0, s1), cvt_pk(s2, s3) };
    *(uint2*)&hsum_out[(blk * 8 + wv) * 256 + lane * 4] = o;
  }
  __syncthreads();

  // MFMA: C[64 rows][32 cols] per wave
  f32x4 acc[4][2] = {};
#pragma unroll
  for (int kb = 0; kb < 8; ++kb) {
    const int kc = kb * 32 + g * 8;
#pragma unroll
    for (int rt = 0; rt < 4; ++rt) {
      bf16x8 a = *(const bf16x8*)&As[swz(rt * 16 + r, kc)];
      acc[rt][0] = __builtin_amdgcn_mfma_f32_16x16x32_bf16(a, wfrag[0][kb], acc[rt][0], 0, 0, 0);
      acc[rt][1] = __builtin_amdgcn_mfma_f32_16x16x32_bf16(a, wfrag[1][kb], acc[rt][1], 0, 0, 0);
    }
  }

  // epilogue: gates + f*nc + in-lane child reduce + 1 shfl; packed u32 stores
#pragma unroll
  for (int rt = 0; rt < 4; ++rt) {
    const int nodeL = rt * 2 + (g >> 1);
    const size_t nodeG = blk * 8 + nodeL;
#pragma unroll
    for (int ct = 0; ct < 2; ++ct) {
      const int col = mb + ct * 16 + r;
      const float base = bias[ct] + bf2f(f_in[nodeG * 256 + col]);
      const float* ncp = nc + (blk * 64 + rt * 16 + g * 4) * 256 + col;
      float s = 0.f;
#pragma unroll
      for (int i = 0; i < 4; ++i)
        s += sigmoidf_(acc[rt][ct][i] + base) * ncp[(size_t)i * 256];
      s += __shfl_xor(s, 16);
      float s2 = __shfl_xor(s, 1);
      if ((g & 1) == 0 && (r & 1) == 0)
        *(unsigned*)&cau_out[nodeG * 512 + col] = cvt_pk(s, s2);
    }
  }
}

// ---------------- k3: iou_aggr GEMM + node func, single barrier --------------
// 16 nodes/block, 8 waves; wave holds (i,o,u) col-triples as 6 register tiles,
// K-quarter reloaded (48 VGPR live). io/cau staged to LDS before the barrier.
__global__ __launch_bounds__(512, 4) void k_final(
    const ushort_t* __restrict__ hsum, const ushort_t* __restrict__ WaggrT,
    const float* __restrict__ b_iou, const float* __restrict__ b_aggr,
    const ushort_t* __restrict__ io_in, const ushort_t* __restrict__ cau_in,
    float* __restrict__ out_h, float* __restrict__ out_c) {
  __shared__ __align__(16) ushort_t As[16 * 256];   // 8 KB
  __shared__ __align__(16) ushort_t Ios[16 * 512];  // 16 KB
  __shared__ __align__(16) ushort_t CUs[16 * 512];  // 16 KB
  const int tid = threadIdx.x;
  const size_t blk = blockIdx.x;                    // 16 nodes
  const int lane = tid & 63, wv = tid >> 6;
  const int g = lane >> 4, r = lane & 15;

  {
    int row = tid >> 5, col = (tid & 31) * 8;
    *(ushort8_t*)&As[swz(row, col)] = ((const ushort8_t*)(hsum + blk * 4096))[tid];
  }
  const ushort8_t* Ig = (const ushort8_t*)(io_in + blk * 8192);
  const ushort8_t* Cg = (const ushort8_t*)(cau_in + blk * 8192);
  ((ushort8_t*)Ios)[tid] = Ig[tid];
  ((ushort8_t*)Ios)[tid + 512] = Ig[tid + 512];
  ((ushort8_t*)CUs)[tid] = Cg[tid];
  ((ushort8_t*)CUs)[tid + 512] = Cg[tid + 512];

  float biasv[3][2];
#pragma unroll
  for (int p = 0; p < 3; ++p)
#pragma unroll
    for (int j = 0; j < 2; ++j) {
      int c = p * 256 + wv * 32 + j * 16 + r;
      biasv[p][j] = b_iou[c] + b_aggr[c];
    }
  __syncthreads();

  f32x4 acc[3][2] = {};
#pragma unroll
  for (int q = 0; q < 4; ++q) {     // K quarters (64 each)
    bf16x8 wf[3][2][2];
#pragma unroll
    for (int p = 0; p < 3; ++p)
#pragma unroll
      for (int j = 0; j < 2; ++j)
#pragma unroll
        for (int kb = 0; kb < 2; ++kb)
          wf[p][j][kb] = *(const bf16x8*)&WaggrT[
              (p * 256 + wv * 32 + j * 16 + r) * 256 + q * 64 + kb * 32 + g * 8];
#pragma unroll
    for (int kb = 0; kb < 2; ++kb) {
      bf16x8 a = *(const bf16x8*)&As[swz(r, q * 64 + kb * 32 + g * 8)];
#pragma unroll
      for (int p = 0; p < 3; ++p)
#pragma unroll
        for (int j = 0; j < 2; ++j)
          acc[p][j] = __builtin_amdgcn_mfma_f32_16x16x32_bf16(a, wf[p][j][kb], acc[p][j], 0, 0, 0);
    }
  }

#pragma unroll
  for (int j = 0; j < 2; ++j)
#pragma unroll
    for (int i = 0; i < 4; ++i) {
      int nl = g * 4 + i;
      int col = wv * 32 + j * 16 + r;
      float iv = acc[0][j][i] + biasv[0][j] + bf2f(Ios[nl * 512 + col]);
      float ov = acc[1][j][i] + biasv[1][j] + bf2f(Ios[nl * 512 + 256 + col]);
      float uv = acc[2][j][i] + biasv[2][j] + bf2f(CUs[nl * 512 + 256 + col]);
      float ca = bf2f(CUs[nl * 512 + col]);
      float cn = sigmoidf_(iv) * tanhf_(uv) + ca;
      size_t node = blk * 16 + nl;
      out_c[node * 256 + col] = cn;
      out_h[node * 256 + col] = sigmoidf_(ov) * tanhf_(cn);
    }
}

extern "C" void kernel_launch(void* const* d_in, const int* in_sizes, int n_in,
                              void* d_out, int out_size, void* d_ws, size_t ws_size,
                              hipStream_t stream) {
  const float* x      = (const float*)d_in[0];
  const float* nh     = (const float*)d_in[1];
  const float* nc     = (const float*)d_in[2];
  const float* W_iou  = (const float*)d_in[3];
  const float* b_iou  = (const float*)d_in[4];
  const float* W_fin  = (const float*)d_in[5];
  const float* b_fin  = (const float*)d_in[6];
  const float* W_f    = (const float*)d_in[7];
  const float* b_f    = (const float*)d_in[8];
  const float* W_aggr = (const float*)d_in[9];
  const float* b_aggr = (const float*)d_in[10];

  char* ws = (char*)d_ws;
  ushort_t* WcatT  = (ushort_t*)ws;                                  // 512 KB
  ushort_t* WfT    = (ushort_t*)(ws + (512 << 10));                  // 128 KB
  ushort_t* WaggrT = (ushort_t*)(ws + (640 << 10));                  // 384 KB
  ushort_t* f_in   = (ushort_t*)(ws + (1 << 20));                    // 16 MB
  ushort_t* hsum   = (ushort_t*)(ws + (1 << 20) + (16 << 20));       // 16 MB

  float* out_h = (float*)d_out;
  float* out_c = out_h + (size_t)NN * HH;
  ushort_t* io_v  = (ushort_t*)out_h;   // per node: [i 256 | o 256] bf16
  ushort_t* cau_v = (ushort_t*)out_c;   // per node: [c_aggr 256 | u 256] bf16

  k_prep<<<2048, 256, 0, stream>>>(W_iou, W_fin, W_f, W_aggr, WcatT, WfT, WaggrT);
  k_iou<<<2048, 256, 0, stream>>>(x, WcatT, b_iou, b_fin, io_v, cau_v, f_in);
  k_fgate<<<4096, 512, 0, stream>>>(nh, nc, WfT, b_f, f_in, cau_v, hsum);
  k_final<<<2048, 512, 0, stream>>>(hsum, WaggrT, b_iou, b_aggr, io_v, cau_v, out_h, out_c);
}

// Round 6
// 324.932 us; speedup vs baseline: 1.0260x; 1.0260x over previous
//
#include <hip/hip_runtime.h>
#include <hip/hip_bf16.h>
#include <stdint.h>

#define NN 32768
#define HH 256

typedef short bf16x8 __attribute__((ext_vector_type(8)));
typedef float f32x4 __attribute__((ext_vector_type(4)));
typedef unsigned short ushort_t;
typedef unsigned short ushort8_t __attribute__((ext_vector_type(8)));
typedef unsigned short ushort4_t __attribute__((ext_vector_type(4)));

__device__ __forceinline__ ushort_t f2bf(float f) {
  union { float f; unsigned u; } v; v.f = f;
  unsigned u = v.u;
  unsigned r = (u + 0x7FFFu + ((u >> 16) & 1u)) >> 16;  // RNE (cold paths)
  return (ushort_t)r;
}
__device__ __forceinline__ float bf2f(ushort_t h) {
  union { unsigned u; float f; } v; v.u = ((unsigned)h) << 16;
  return v.f;
}
__device__ __forceinline__ float asf(unsigned u) {
  union { unsigned u; float f; } v; v.u = u; return v.f;
}
// HW packed f32->bf16 (RNE), 1 instr per 2 elems
__device__ __forceinline__ unsigned cvt_pk(float lo, float hi) {
  unsigned r;
  asm("v_cvt_pk_bf16_f32 %0, %1, %2" : "=v"(r) : "v"(lo), "v"(hi));
  return r;
}
__device__ __forceinline__ float sigmoidf_(float x) {
  float e = __builtin_amdgcn_exp2f(-1.4426950408889634f * x);
  return __builtin_amdgcn_rcpf(1.f + e);
}
__device__ __forceinline__ float tanhf_(float x) {
  float ax = fminf(fabsf(x), 15.f);
  float e = __builtin_amdgcn_exp2f(2.8853900817779268f * ax);  // exp(2ax)
  float t = (e - 1.f) * __builtin_amdgcn_rcpf(e + 1.f);
  return copysignf(t, x);
}
// XOR swizzle: 16B chunks within a 256-elem (512B) row, spread across rows&7
__device__ __forceinline__ int swz(int row, int col) {
  return row * 256 + ((((col >> 3) ^ (row & 7)) << 3) | (col & 7));
}

// ---------------- prep: weights -> bf16, transposed to [N][K] ----------------
__global__ void k_prep(const float* __restrict__ W_iou, const float* __restrict__ W_fin,
                       const float* __restrict__ W_f, const float* __restrict__ W_aggr,
                       ushort_t* __restrict__ WcatT, ushort_t* __restrict__ WfT,
                       ushort_t* __restrict__ WaggrT) {
  int tid = blockIdx.x * 256 + threadIdx.x;
  if (tid < 262144) {                       // WcatT [1024][256]
    int n = tid >> 8, k = tid & 255;
    float v = (n < 768) ? W_iou[k * 768 + n] : W_fin[k * 256 + (n - 768)];
    WcatT[tid] = f2bf(v);
  } else if (tid < 327680) {                // WfT [256][256]
    int t2 = tid - 262144; int n = t2 >> 8, k = t2 & 255;
    WfT[t2] = f2bf(W_f[k * 256 + n]);
  } else if (tid < 524288) {                // WaggrT [768][256]
    int t3 = tid - 327680; int n = t3 >> 8, k = t3 & 255;
    WaggrT[t3] = f2bf(W_aggr[k * 768 + n]);
  }
}

// ---------------- k1: iouf = x @ [W_iou | W_fin] + bias ---------------------- 
__global__ __launch_bounds__(256) void k_iou(
    const float* __restrict__ x, const ushort_t* __restrict__ WcatT,
    const float* __restrict__ b_iou, const float* __restrict__ b_fin,
    ushort_t* __restrict__ io_out, ushort_t* __restrict__ cau_out,
    ushort_t* __restrict__ f_out) {
  __shared__ __align__(16) ushort_t As[64 * 256];
  __shared__ __align__(16) ushort_t Bs[64 * 256];
  __shared__ float bias_s[64];
  const int tid = threadIdx.x;
  const int mt = blockIdx.x >> 2;
  const int nt = blockIdx.x & 3;

  const float4* Ag = (const float4*)(x + (size_t)mt * 64 * 256);
#pragma unroll
  for (int it = 0; it < 16; ++it) {
    int idx4 = tid + it * 256;
    float4 v = Ag[idx4];
    int row = idx4 >> 6, col = (idx4 & 63) << 2;
    uint2 b = { cvt_pk(v.x, v.y), cvt_pk(v.z, v.w) };
    *(uint2*)&As[swz(row, col)] = b;
  }

  const int lane = tid & 63, wv = tid >> 6;
  const int g = lane >> 4, r = lane & 15;
  const int wm = wv >> 1, wn = wv & 1;

  for (int s = 0; s < 4; ++s) {
    __syncthreads();
    const int ct = nt * 4 + s;  // 64-col tile index in [0,16)
    const ushort8_t* Bg = (const ushort8_t*)(WcatT + (size_t)ct * 64 * 256);
#pragma unroll
    for (int it = 0; it < 8; ++it) {
      int idx8 = tid + it * 256;
      int row = idx8 >> 5, col = (idx8 & 31) << 3;
      *(ushort8_t*)&Bs[swz(row, col)] = Bg[idx8];
    }
    if (tid < 64) {
      int c = ct * 64 + tid;
      bias_s[tid] = (c < 768) ? b_iou[c] : b_fin[c - 768];
    }
    __syncthreads();

    f32x4 acc[2][2] = {};
#pragma unroll
    for (int kb = 0; kb < 8; ++kb) {
      int kc = kb * 32 + g * 8;
      bf16x8 a0 = *(const bf16x8*)&As[swz(wm * 32 + r, kc)];
      bf16x8 a1 = *(const bf16x8*)&As[swz(wm * 32 + 16 + r, kc)];
      bf16x8 b0 = *(const bf16x8*)&Bs[swz(wn * 32 + r, kc)];
      bf16x8 b1 = *(const bf16x8*)&Bs[swz(wn * 32 + 16 + r, kc)];
      acc[0][0] = __builtin_amdgcn_mfma_f32_16x16x32_bf16(a0, b0, acc[0][0], 0, 0, 0);
      acc[0][1] = __builtin_amdgcn_mfma_f32_16x16x32_bf16(a0, b1, acc[0][1], 0, 0, 0);
      acc[1][0] = __builtin_amdgcn_mfma_f32_16x16x32_bf16(a1, b0, acc[1][0], 0, 0, 0);
      acc[1][1] = __builtin_amdgcn_mfma_f32_16x16x32_bf16(a1, b1, acc[1][1], 0, 0, 0);
    }
#pragma unroll
    for (int mi = 0; mi < 2; ++mi)
#pragma unroll
      for (int ni = 0; ni < 2; ++ni)
#pragma unroll
        for (int i = 0; i < 4; ++i) {
          int node = mt * 64 + wm * 32 + mi * 16 + g * 4 + i;
          int colL = wn * 32 + ni * 16 + r;
          int col = ct * 64 + colL;
          ushort_t hv = f2bf(acc[mi][ni][i] + bias_s[colL]);
          if (col < 512)      io_out[node * 512 + col] = hv;
          else if (col < 768) cau_out[node * 512 + (col - 256)] = hv;
          else                f_out[node * 256 + (col - 768)] = hv;
        }
  }
}

// ---------------- k2: f-path v5 — 16 waves, 16 cols/wave, reg-budget <=128 ---
// wfrag = 8 x bf16x8 = 32 VGPR (resident); nc/f_in prefetched pre-MFMA.
// Staging/hsum: waves 0-7 (wave = node), 2 batches of 4 children.
__global__ __launch_bounds__(1024, 4) void k_fgate(
    const float* __restrict__ nh, const float* __restrict__ nc,
    const ushort_t* __restrict__ WfT, const float* __restrict__ b_f,
    const ushort_t* __restrict__ f_in,
    ushort_t* __restrict__ cau_out, ushort_t* __restrict__ hsum_out) {
  __shared__ __align__(16) ushort_t As[64 * 256];   // 32 KB
  const int tid = threadIdx.x;
  const size_t blk = blockIdx.x;                    // 64 rows per block
  const int lane = tid & 63, wv = tid >> 6;         // wv 0..15
  const int g = lane >> 4, r = lane & 15;
  const int col = wv * 16 + r;                      // lane's output col

  // W_f^T fragments (B-operand), 32 VGPR, live through MFMA
  bf16x8 wfrag[8];
#pragma unroll
  for (int kb = 0; kb < 8; ++kb)
    wfrag[kb] = *(const bf16x8*)&WfT[col * 256 + kb * 32 + g * 8];
  const float bias = b_f[col];

  // staging + fused f32 hsum: waves 0-7, wave = node, lane = col-quad
  if (wv < 8) {
    const float* src = nh + (blk * 64 + wv * 8) * 256 + lane * 4;
    float s0 = 0.f, s1 = 0.f, s2 = 0.f, s3 = 0.f;
#pragma unroll
    for (int bb = 0; bb < 2; ++bb) {
      float4 v[4];
#pragma unroll
      for (int c = 0; c < 4; ++c) v[c] = *(const float4*)(src + (size_t)(bb * 4 + c) * 256);
#pragma unroll
      for (int c = 0; c < 4; ++c) {
        uint2 p = { cvt_pk(v[c].x, v[c].y), cvt_pk(v[c].z, v[c].w) };
        *(uint2*)&As[swz(wv * 8 + bb * 4 + c, lane * 4)] = p;
        s0 += v[c].x; s1 += v[c].y; s2 += v[c].z; s3 += v[c].w;
      }
    }
    uint2 o = { cvt_pk(s0, s1), cvt_pk(s2, s3) };
    *(uint2*)&hsum_out[(blk * 8 + wv) * 256 + lane * 4] = o;
  }
  __syncthreads();

  // prefetch nc + f_in; latency hides under ds_read + MFMA below
  float ncv[4][4];
  float fvv[4];
#pragma unroll
  for (int rt = 0; rt < 4; ++rt) {
    const int nodeL = rt * 2 + (g >> 1);
    fvv[rt] = bf2f(f_in[(blk * 8 + nodeL) * 256 + col]);
    const float* ncp = nc + (blk * 64 + rt * 16 + g * 4) * 256 + col;
#pragma unroll
    for (int i = 0; i < 4; ++i) ncv[rt][i] = ncp[(size_t)i * 256];
  }

  // MFMA: C[64 rows][16 cols] per wave
  f32x4 acc[4] = {};
#pragma unroll
  for (int kb = 0; kb < 8; ++kb) {
    const int kc = kb * 32 + g * 8;
#pragma unroll
    for (int rt = 0; rt < 4; ++rt) {
      bf16x8 a = *(const bf16x8*)&As[swz(rt * 16 + r, kc)];
      acc[rt] = __builtin_amdgcn_mfma_f32_16x16x32_bf16(a, wfrag[kb], acc[rt], 0, 0, 0);
    }
  }

  // epilogue: gates + f*nc + in-lane child reduce + 1 shfl; packed u32 stores
#pragma unroll
  for (int rt = 0; rt < 4; ++rt) {
    const int nodeL = rt * 2 + (g >> 1);
    const size_t nodeG = blk * 8 + nodeL;
    const float base = bias + fvv[rt];
    float s = 0.f;
#pragma unroll
    for (int i = 0; i < 4; ++i)
      s += sigmoidf_(acc[rt][i] + base) * ncv[rt][i];
    s += __shfl_xor(s, 16);
    float s2 = __shfl_xor(s, 1);
    if (((g & 1) == 0) && ((r & 1) == 0))
      *(unsigned*)&cau_out[nodeG * 512 + col] = cvt_pk(s, s2);
  }
}

// ---------------- k3: iou_aggr GEMM + node func, single barrier --------------
__global__ __launch_bounds__(512, 4) void k_final(
    const ushort_t* __restrict__ hsum, const ushort_t* __restrict__ WaggrT,
    const float* __restrict__ b_iou, const float* __restrict__ b_aggr,
    const ushort_t* __restrict__ io_in, const ushort_t* __restrict__ cau_in,
    float* __restrict__ out_h, float* __restrict__ out_c) {
  __shared__ __align__(16) ushort_t As[16 * 256];   // 8 KB
  __shared__ __align__(16) ushort_t Ios[16 * 512];  // 16 KB
  __shared__ __align__(16) ushort_t CUs[16 * 512];  // 16 KB
  const int tid = threadIdx.x;
  const size_t blk = blockIdx.x;                    // 16 nodes
  const int lane = tid & 63, wv = tid >> 6;
  const int g = lane >> 4, r = lane & 15;

  {
    int row = tid >> 5, col = (tid & 31) * 8;
    *(ushort8_t*)&As[swz(row, col)] = ((const ushort8_t*)(hsum + blk * 4096))[tid];
  }
  const ushort8_t* Ig = (const ushort8_t*)(io_in + blk * 8192);
  const ushort8_t* Cg = (const ushort8_t*)(cau_in + blk * 8192);
  ((ushort8_t*)Ios)[tid] = Ig[tid];
  ((ushort8_t*)Ios)[tid + 512] = Ig[tid + 512];
  ((ushort8_t*)CUs)[tid] = Cg[tid];
  ((ushort8_t*)CUs)[tid + 512] = Cg[tid + 512];

  float biasv[3][2];
#pragma unroll
  for (int p = 0; p < 3; ++p)
#pragma unroll
    for (int j = 0; j < 2; ++j) {
      int c = p * 256 + wv * 32 + j * 16 + r;
      biasv[p][j] = b_iou[c] + b_aggr[c];
    }
  __syncthreads();

  f32x4 acc[3][2] = {};
#pragma unroll
  for (int q = 0; q < 4; ++q) {     // K quarters (64 each)
    bf16x8 wf[3][2][2];
#pragma unroll
    for (int p = 0; p < 3; ++p)
#pragma unroll
      for (int j = 0; j < 2; ++j)
#pragma unroll
        for (int kb = 0; kb < 2; ++kb)
          wf[p][j][kb] = *(const bf16x8*)&WaggrT[
              (p * 256 + wv * 32 + j * 16 + r) * 256 + q * 64 + kb * 32 + g * 8];
#pragma unroll
    for (int kb = 0; kb < 2; ++kb) {
      bf16x8 a = *(const bf16x8*)&As[swz(r, q * 64 + kb * 32 + g * 8)];
#pragma unroll
      for (int p = 0; p < 3; ++p)
#pragma unroll
        for (int j = 0; j < 2; ++j)
          acc[p][j] = __builtin_amdgcn_mfma_f32_16x16x32_bf16(a, wf[p][j][kb], acc[p][j], 0, 0, 0);
    }
  }

#pragma unroll
  for (int j = 0; j < 2; ++j)
#pragma unroll
    for (int i = 0; i < 4; ++i) {
      int nl = g * 4 + i;
      int col = wv * 32 + j * 16 + r;
      float iv = acc[0][j][i] + biasv[0][j] + bf2f(Ios[nl * 512 + col]);
      float ov = acc[1][j][i] + biasv[1][j] + bf2f(Ios[nl * 512 + 256 + col]);
      float uv = acc[2][j][i] + biasv[2][j] + bf2f(CUs[nl * 512 + 256 + col]);
      float ca = bf2f(CUs[nl * 512 + col]);
      float cn = sigmoidf_(iv) * tanhf_(uv) + ca;
      size_t node = blk * 16 + nl;
      out_c[node * 256 + col] = cn;
      out_h[node * 256 + col] = sigmoidf_(ov) * tanhf_(cn);
    }
}

extern "C" void kernel_launch(void* const* d_in, const int* in_sizes, int n_in,
                              void* d_out, int out_size, void* d_ws, size_t ws_size,
                              hipStream_t stream) {
  const float* x      = (const float*)d_in[0];
  const float* nh     = (const float*)d_in[1];
  const float* nc     = (const float*)d_in[2];
  const float* W_iou  = (const float*)d_in[3];
  const float* b_iou  = (const float*)d_in[4];
  const float* W_fin  = (const float*)d_in[5];
  const float* b_fin  = (const float*)d_in[6];
  const float* W_f    = (const float*)d_in[7];
  const float* b_f    = (const float*)d_in[8];
  const float* W_aggr = (const float*)d_in[9];
  const float* b_aggr = (const float*)d_in[10];

  char* ws = (char*)d_ws;
  ushort_t* WcatT  = (ushort_t*)ws;                                  // 512 KB
  ushort_t* WfT    = (ushort_t*)(ws + (512 << 10));                  // 128 KB
  ushort_t* WaggrT = (ushort_t*)(ws + (640 << 10));                  // 384 KB
  ushort_t* f_in   = (ushort_t*)(ws + (1 << 20));                    // 16 MB
  ushort_t* hsum   = (ushort_t*)(ws + (1 << 20) + (16 << 20));       // 16 MB

  float* out_h = (float*)d_out;
  float* out_c = out_h + (size_t)NN * HH;
  ushort_t* io_v  = (ushort_t*)out_h;   // per node: [i 256 | o 256] bf16
  ushort_t* cau_v = (ushort_t*)out_c;   // per node: [c_aggr 256 | u 256] bf16

  k_prep<<<2048, 256, 0, stream>>>(W_iou, W_fin, W_f, W_aggr, WcatT, WfT, WaggrT);
  k_iou<<<2048, 256, 0, stream>>>(x, WcatT, b_iou, b_fin, io_v, cau_v, f_in);
  k_fgate<<<4096, 1024, 0, stream>>>(nh, nc, WfT, b_f, f_in, cau_v, hsum);
  k_final<<<2048, 512, 0, stream>>>(hsum, WaggrT, b_iou, b_aggr, io_v, cau_v, out_h, out_c);
}